// Round 1
// baseline (363.595 us; speedup 1.0000x reference)
//
#include <hip/hip_runtime.h>
#include <hip/hip_cooperative_groups.h>

namespace cg = cooperative_groups;

// ---------------- problem constants ----------------
#define N13E 16224      // 32*3*169
#define N26E 64896      // 32*3*676
#define NTOT 340704
#define BASE26 16224
#define BASE52 81120
#define KMAX 2048
#define TOPK 512
#define GRID 256
#define BLOCK 512
#define GTHREADS (GRID * BLOCK)   // 131072

__device__ __forceinline__ float sigm(float x) { return 1.0f / (1.0f + expf(-x)); }

__device__ __forceinline__ unsigned long long pack_key(float v, int c) {
    unsigned u = __float_as_uint(v);
    unsigned ov = (u & 0x80000000u) ? ~u : (u | 0x80000000u);
    return (((unsigned long long)ov) << 32) | (unsigned long long)(unsigned)(127 - c);
}

// conf logit load + candidate-index computation (validated index math from K1/K2)
template <int HW, int BASE>
__device__ __forceinline__ void conf_one(const float* __restrict__ p, int local,
                                         unsigned& bits, unsigned& concat, bool& pass) {
    int ba = local / HW;           // b*3 + a
    int hw = local - ba * HW;
    int b = ba / 3;
    int a = ba - b * 3;
    float logit = p[(b * 255 + a * 85 + 4) * HW + hw];
    float conf = sigm(logit);
    if (conf > 0.5f) {
        pass = true;
        bits = __float_as_uint(conf);
        concat = (unsigned)(BASE + (b * HW + hw) * 3 + a);
    }
}

// decode one box with 64 lanes (R4/R5-validated body, unchanged)
template <int HW, int W>
__device__ __forceinline__ void decode64(const float* __restrict__ p, int local, float strideF,
                                         float aw0, float ah0, float aw1, float ah1, float aw2, float ah2,
                                         float conf, float* __restrict__ outrow, int lane) {
    int a = local % 3;
    int cell = local / 3;
    int b = cell / HW;
    int hw = cell - b * HW;
    int h = hw / W;
    int wc = hw - h * W;
    int cb = b * 255 + a * 85;
    float v1 = p[(cb + 5 + lane) * HW + hw];
    unsigned long long k1 = pack_key(v1, lane);
    if (lane < 16) {
        float v2 = p[(cb + 69 + lane) * HW + hw];   // classes 64..79
        unsigned long long k2 = pack_key(v2, lane + 64);
        if (k2 > k1) k1 = k2;
    }
#pragma unroll
    for (int m = 32; m >= 1; m >>= 1) {
        unsigned long long o = __shfl_xor(k1, m, 64);
        if (o > k1) k1 = o;
    }
    if (lane == 0) {
        int cls = 127 - (int)(unsigned)(k1 & 0xFFFFFFFFull);
        float t0 = p[(cb + 0) * HW + hw];
        float t1 = p[(cb + 1) * HW + hw];
        float t2 = p[(cb + 2) * HW + hw];
        float t3 = p[(cb + 3) * HW + hw];
        float aw = (a == 0) ? aw0 : ((a == 1) ? aw1 : aw2);
        float ah = (a == 0) ? ah0 : ((a == 1) ? ah1 : ah2);
        float sx = sigm(t0);
        float sy = sigm(t1);
        float bw = aw * expf(t2);
        float bh = ah * expf(t3);
        float cx = ((float)wc + sx) * strideF;
        float cy = ((float)h + sy) * strideF;
        float w0 = bw * 0.5f, h0 = bh * 0.5f;
        outrow[0] = conf;
        outrow[1] = cx - w0;
        outrow[2] = cy - h0;
        outrow[3] = cx + w0;
        outrow[4] = cy + h0;
        outrow[5] = (float)cls;
        outrow[6] = (float)b;
    }
}

// LDS is reused across phases (phases separated by grid.sync ⇒ block-level sync too)
union SharedU {
    struct { unsigned tot[BLOCK]; unsigned thrS; } scan;                                    // ~2 KB
    struct { unsigned long long keysL[KMAX]; unsigned long long sortedL[2]; } rank;         // ~16 KB
    struct { float sx1[TOPK]; float sy1[TOPK]; float sx2[TOPK]; float sy2[TOPK]; } mask;    // 8 KB
    struct { unsigned long long smask[TOPK * 8]; unsigned long long live[8];
             unsigned long long keepw[8]; } sweep;                                          // ~32 KB
};

__global__ void __launch_bounds__(BLOCK, 2) k_fused(
    const float* __restrict__ p13, const float* __restrict__ p26, const float* __restrict__ p52,
    unsigned* __restrict__ hist, unsigned* __restrict__ cnt,
    unsigned long long* __restrict__ keys, float* __restrict__ cand,
    unsigned long long* __restrict__ smaskG, float* __restrict__ out) {

    cg::grid_group grid = cg::this_grid();
    __shared__ SharedU sh;
    int tid = threadIdx.x;
    int gid = blockIdx.x * BLOCK + tid;

    // ===== phase 1: zero hist/cnt; load conf logits into registers (grid-stride, ≤3/thread) =====
    if (gid < 2048) hist[gid] = 0u;
    if (gid == 2048) *cnt = 0u;

    unsigned bits0 = 0, bits1 = 0, bits2 = 0;
    unsigned conc0 = 0, conc1 = 0, conc2 = 0;
    bool pass0 = false, pass1 = false, pass2 = false;
    {   // element gid: any region
        int e = gid;
        if (e < N13E)             conf_one<169, 0>(p13, e, bits0, conc0, pass0);
        else if (e < N13E + N26E) conf_one<676, BASE26>(p26, e - N13E, bits0, conc0, pass0);
        else                      conf_one<2704, BASE52>(p52, e - (N13E + N26E), bits0, conc0, pass0);
    }
    {   // element gid + 131072: always in the 52x52 region (>= 81120), always < NTOT
        int e = gid + GTHREADS;
        conf_one<2704, BASE52>(p52, e - (N13E + N26E), bits1, conc1, pass1);
    }
    {   // element gid + 262144: 52x52 region, tail-guarded
        int e = gid + 2 * GTHREADS;
        if (e < NTOT) conf_one<2704, BASE52>(p52, e - (N13E + N26E), bits2, conc2, pass2);
    }
    grid.sync();

    // ===== phase 2: global histogram of conf bits (R3-validated binning) =====
    {
        if (pass0) { unsigned bin = (bits0 >> 12) - 0x3F000u; bin = (bin > 2047u) ? 2047u : bin; atomicAdd(&hist[bin], 1u); }
        if (pass1) { unsigned bin = (bits1 >> 12) - 0x3F000u; bin = (bin > 2047u) ? 2047u : bin; atomicAdd(&hist[bin], 1u); }
        if (pass2) { unsigned bin = (bits2 >> 12) - 0x3F000u; bin = (bin > 2047u) ? 2047u : bin; atomicAdd(&hist[bin], 1u); }
    }
    grid.sync();

    // ===== phase 3: per-block threshold scan (R3-validated) + compact from register cache =====
    {
        unsigned loc[4]; unsigned s = 0u;
#pragma unroll
        for (int k = 0; k < 4; ++k) { loc[k] = hist[2047 - (tid * 4 + k)]; s += loc[k]; }
        sh.scan.tot[tid] = s;
        __syncthreads();
        for (int off = 1; off < BLOCK; off <<= 1) {
            unsigned u = (tid >= off) ? sh.scan.tot[tid - off] : 0u;
            __syncthreads();
            sh.scan.tot[tid] += u;
            __syncthreads();
        }
        unsigned excl = sh.scan.tot[tid] - s;
        unsigned total = sh.scan.tot[BLOCK - 1];
        if (total < (unsigned)TOPK) {
            if (tid == 0) sh.scan.thrS = 0x3F000001u;     // accept every conf > 0.5
        } else {
            unsigned run = excl;
#pragma unroll
            for (int k = 0; k < 4; ++k) {
                unsigned c = run + loc[k];
                if (run < (unsigned)TOPK && c >= (unsigned)TOPK) {  // unique crossing
                    int bin = 2047 - (tid * 4 + k);
                    sh.scan.thrS = ((unsigned)(bin + 0x3F000)) << 12;
                }
                run = c;
            }
        }
        __syncthreads();
        unsigned thrv = sh.scan.thrS;
        if (pass0 && bits0 >= thrv) {
            unsigned pos = atomicAdd(cnt, 1u);
            if (pos < (unsigned)KMAX)
                keys[pos] = (((unsigned long long)bits0) << 32) | (unsigned long long)(0xFFFFFFFFu - conc0);
        }
        if (pass1 && bits1 >= thrv) {
            unsigned pos = atomicAdd(cnt, 1u);
            if (pos < (unsigned)KMAX)
                keys[pos] = (((unsigned long long)bits1) << 32) | (unsigned long long)(0xFFFFFFFFu - conc1);
        }
        if (pass2 && bits2 >= thrv) {
            unsigned pos = atomicAdd(cnt, 1u);
            if (pos < (unsigned)KMAX)
                keys[pos] = (((unsigned long long)bits2) << 32) | (unsigned long long)(0xFFFFFFFFu - conc2);
        }
    }
    grid.sync();

    // ===== phase 4: rank-select (2 boxes/block × 256 blocks) + decode (R4/R5-validated) =====
    {
        unsigned n = *cnt; if (n > (unsigned)KMAX) n = (unsigned)KMAX;
        int npad = ((int)n + 7) & ~7;
        for (int j = tid; j < npad; j += BLOCK) sh.rank.keysL[j] = (j < (int)n) ? keys[j] : 0ull;
        if (tid < 2) sh.rank.sortedL[tid] = 0ull;
        __syncthreads();
        int lo = blockIdx.x * 2;                  // rank range [lo, lo+2)
        unsigned long long mine[4]; unsigned rk[4]; int nown = 0;
#pragma unroll
        for (int k = 0; k < 4; ++k) {
            int idx = tid + k * BLOCK;
            if (idx < (int)n) { mine[nown] = sh.rank.keysL[idx]; rk[nown] = 0u; ++nown; }
        }
        for (int j = 0; j < npad; j += 8) {       // 8-wide unroll: independent LDS loads
            unsigned long long kk[8];
#pragma unroll
            for (int u = 0; u < 8; ++u) kk[u] = sh.rank.keysL[j + u];
            for (int m = 0; m < nown; ++m) {
                unsigned acc = 0u;
#pragma unroll
                for (int u = 0; u < 8; ++u) acc += (kk[u] > mine[m]) ? 1u : 0u;
                rk[m] += acc;
            }
        }
        for (int m = 0; m < nown; ++m) {
            unsigned r = rk[m];
            if (r >= (unsigned)lo && r < (unsigned)(lo + 2)) sh.rank.sortedL[r - lo] = mine[m];
        }
        __syncthreads();

        int bb = tid >> 6;
        int lane = tid & 63;
        if (bb < 2) {
            int box = lo + bb;
            unsigned long long key = sh.rank.sortedL[bb];
            unsigned sb = (unsigned)(key >> 32);
            float* row = cand + box * 7;
            if (sb == 0u) {
                if (lane < 7) row[lane] = 0.0f;
            } else {
                unsigned idx = 0xFFFFFFFFu - (unsigned)(key & 0xFFFFFFFFull);
                float conf = __uint_as_float(sb);
                if (idx < N13E)
                    decode64<169, 13>(p13, (int)idx, 32.0f, 116.f, 90.f, 156.f, 198.f, 373.f, 326.f, conf, row, lane);
                else if (idx < N13E + N26E)
                    decode64<676, 26>(p26, (int)idx - BASE26, 16.0f, 30.f, 61.f, 62.f, 45.f, 59.f, 119.f, conf, row, lane);
                else
                    decode64<2704, 52>(p52, (int)idx - BASE52, 8.0f, 10.f, 13.f, 16.f, 30.f, 33.f, 23.f, conf, row, lane);
            }
        }
    }
    grid.sync();

    // ===== phase 5: suppression mask, 2 words/wave × 2048 waves (R4-P4-validated body) =====
    {
        for (int p = tid; p < TOPK; p += BLOCK) {
            const float* r = cand + p * 7;
            sh.mask.sx1[p] = r[1]; sh.mask.sy1[p] = r[2]; sh.mask.sx2[p] = r[3]; sh.mask.sy2[p] = r[4];
        }
        __syncthreads();
        int wv = tid >> 6;
        int lane = tid & 63;
        int gwave = blockIdx.x * 8 + wv;          // 0..2047
#pragma unroll
        for (int q = 0; q < 2; ++q) {
            int word = gwave * 2 + q;             // 0..4095
            int i = word >> 3, jw = word & 7;
            int j = jw * 64 + lane;
            float ix1 = sh.mask.sx1[i], iy1 = sh.mask.sy1[i], ix2 = sh.mask.sx2[i], iy2 = sh.mask.sy2[i];
            float ai = fmaxf(ix2 - ix1, 0.f) * fmaxf(iy2 - iy1, 0.f);
            float jx1 = sh.mask.sx1[j], jy1 = sh.mask.sy1[j], jx2 = sh.mask.sx2[j], jy2 = sh.mask.sy2[j];
            float aj = fmaxf(jx2 - jx1, 0.f) * fmaxf(jy2 - jy1, 0.f);
            float xx1 = fmaxf(ix1, jx1), yy1 = fmaxf(iy1, jy1);
            float xx2 = fminf(ix2, jx2), yy2 = fminf(iy2, jy2);
            float inter = fmaxf(xx2 - xx1, 0.f) * fmaxf(yy2 - yy1, 0.f);
            float iou = inter / (((ai + aj) - inter) + 1e-9f);
            bool bit = (j > i) && (iou > 0.3f);
            unsigned long long m = __ballot(bit);
            if (lane == 0) smaskG[word] = m;
        }
    }
    grid.sync();

    // ===== phase 6: serial greedy sweep + masked output, block 0 only (R4-P5-validated) =====
    if (blockIdx.x == 0) {
        for (int p = tid; p < TOPK * 8; p += BLOCK) sh.sweep.smask[p] = smaskG[p];
        bool validt = cand[tid * 7] > 0.5f;
        unsigned long long bal = __ballot(validt);
        if ((tid & 63) == 0) sh.sweep.live[tid >> 6] = bal;
        __syncthreads();
        if (tid < 64) {
            int lane = tid;
            int lw = lane & 7;
            unsigned long long r = 0ull;
#pragma unroll
            for (int w = 0; w < 8; ++w) {
                unsigned long long lvw = sh.sweep.live[w];
#pragma unroll 8
                for (int b2 = 0; b2 < 64; ++b2) {
                    int i = w * 64 + b2;
                    unsigned long long rowv = sh.sweep.smask[i * 8 + lw];
                    unsigned rlo = (unsigned)__builtin_amdgcn_readlane((int)(unsigned)(r & 0xFFFFFFFFull), w);
                    unsigned rhi = (unsigned)__builtin_amdgcn_readlane((int)(unsigned)(r >> 32), w);
                    unsigned long long rw = (((unsigned long long)rhi) << 32) | (unsigned long long)rlo;
                    bool acc = (((lvw >> b2) & 1ull) != 0ull) && (((rw >> b2) & 1ull) == 0ull);
                    if (acc) r |= rowv;
                }
            }
            if (lane < 8) sh.sweep.keepw[lane] = sh.sweep.live[lane] & ~r;
        }
        __syncthreads();
        for (int p = tid; p < TOPK * 7; p += BLOCK) {
            int i = p / 7;
            unsigned long long kb = (sh.sweep.keepw[i >> 6] >> (i & 63)) & 1ull;
            out[p] = kb ? cand[p] : 0.0f;
        }
    }
}

// ---------------- launch: ONE cooperative dispatch ----------------
extern "C" void kernel_launch(void* const* d_in, const int* in_sizes, int n_in,
                              void* d_out, int out_size, void* d_ws, size_t ws_size,
                              hipStream_t stream) {
    const float* p13 = (const float*)d_in[0];
    const float* p26 = (const float*)d_in[1];
    const float* p52 = (const float*)d_in[2];
    float* out = (float*)d_out;
    char* ws = (char*)d_ws;

    unsigned* hist             = (unsigned*)(ws + 0);                // 2048 u32
    unsigned* cnt              = (unsigned*)(ws + 8192);             // 1 u32
    unsigned long long* keys   = (unsigned long long*)(ws + 8704);   // 2048 u64
    float* cand                = (float*)(ws + 25088);               // 512*7 f32
    unsigned long long* smaskG = (unsigned long long*)(ws + 39936);  // 4096 u64

    void* args[] = { (void*)&p13, (void*)&p26, (void*)&p52,
                     (void*)&hist, (void*)&cnt, (void*)&keys,
                     (void*)&cand, (void*)&smaskG, (void*)&out };
    hipLaunchCooperativeKernel((const void*)k_fused, dim3(GRID), dim3(BLOCK),
                               args, 0, stream);
}